// Round 11
// baseline (59.749 us; speedup 1.0000x reference)
//
#include <hip/hip_runtime.h>
#include <cstdint>
#include <cstddef>

typedef __attribute__((ext_vector_type(8))) short short8;
typedef __attribute__((ext_vector_type(4))) unsigned short ushort4_t;
typedef __attribute__((ext_vector_type(16))) float f32x16;

#define NF 40
#define NK 780           // 40*39/2 pairs
#define BT 64            // batch rows per block
#define THREADS 1024     // 16 waves
// grid 256 = 128 btiles x 2 k-halves; khalf = bid>>7 so pair-mates share an XCD

__device__ __forceinline__ unsigned short f2bf(float f) {
    unsigned int u = __float_as_uint(f);
    u = (u + 0x7fffu + ((u >> 16) & 1u)) >> 16;
    return (unsigned short)u;
}
__device__ __forceinline__ float bf2f(unsigned short x) {
    return __uint_as_float(((unsigned int)x) << 16);
}

// wfrag[k][half][l][t] = bf16( W[k][ e = l&31 ][ 16*half + 8*(l>>5) + t ] )
__global__ __launch_bounds__(128) void wprep_kernel(const float* __restrict__ W,
                                                    unsigned short* __restrict__ wfrag) {
    const int k = blockIdx.x, t = threadIdx.x;
    const int half = t >> 6, l = t & 63;
    const int e = l & 31;
    const int f0 = 16 * half + 8 * (l >> 5);
    const float* src = W + (size_t)k * 1024 + e * 32 + f0;
    const float4 x0 = *(const float4*)src;
    const float4 x1 = *(const float4*)(src + 4);
    short8 v;
    v[0] = (short)f2bf(x0.x); v[1] = (short)f2bf(x0.y);
    v[2] = (short)f2bf(x0.z); v[3] = (short)f2bf(x0.w);
    v[4] = (short)f2bf(x1.x); v[5] = (short)f2bf(x1.y);
    v[6] = (short)f2bf(x1.z); v[7] = (short)f2bf(x1.w);
    *(short8*)(wfrag + (size_t)k * 1024 + half * 512 + l * 8) = v;
}

// --- forced-pipeline primitives -------------------------------------------------
__device__ __forceinline__ void ld_w4(short8& r0, short8& r1, short8& r2, short8& r3,
                                      const char* addr) {
    asm volatile("global_load_dwordx4 %0, %4, off\n\t"
                 "global_load_dwordx4 %1, %4, off offset:1024\n\t"
                 "global_load_dwordx4 %2, %4, off offset:2048\n\t"
                 "global_load_dwordx4 %3, %4, off offset:3072"
                 : "=&v"(r0), "=&v"(r1), "=&v"(r2), "=&v"(r3)
                 : "v"(addr));
}
#define WAITP() do { asm volatile("s_waitcnt vmcnt(4)" ::: "memory"); \
                     __builtin_amdgcn_sched_barrier(0); } while (0)
#define WAIT0() do { asm volatile("s_waitcnt vmcnt(0)" ::: "memory"); \
                     __builtin_amdgcn_sched_barrier(0); } while (0)

#define LOADW2(R0, R1, R2, R3, KB)                                                      \
    {                                                                                   \
        const int kbc = (KB) > 778 ? 778 : (KB);                                        \
        ld_w4(R0, R1, R2, R3, wbase + ((size_t)kbc << 11));                             \
    }

// embT granule (field, g): g = (b + 64*fq) ^ (field&7); holds bf16 of
// emb[b0+b][field][8*fq..8*fq+7]. 4096 B per field.

#define RELOAD_VI()                                                                     \
    {                                                                                   \
        const int i7 = ii & 7;                                                          \
        const char* ibase = embT + (ii << 12) + eoff;                                   \
        const ushort4_t a0_ = *(const ushort4_t*)(ibase + (((b32      ) ^ i7) << 4));   \
        const ushort4_t a1_ = *(const ushort4_t*)(ibase + (((b32 +  64) ^ i7) << 4));   \
        const ushort4_t a2_ = *(const ushort4_t*)(ibase + (((b32 + 128) ^ i7) << 4));   \
        const ushort4_t a3_ = *(const ushort4_t*)(ibase + (((b32 + 192) ^ i7) << 4));   \
        const ushort4_t b0_ = *(const ushort4_t*)(ibase + (((b32 +  32) ^ i7) << 4));   \
        const ushort4_t b1_ = *(const ushort4_t*)(ibase + (((b32 +  96) ^ i7) << 4));   \
        const ushort4_t b2_ = *(const ushort4_t*)(ibase + (((b32 + 160) ^ i7) << 4));   \
        const ushort4_t b3_ = *(const ushort4_t*)(ibase + (((b32 + 224) ^ i7) << 4));   \
        uA0 = bf2f(a0_[0]); uA1 = bf2f(a0_[1]); uA2  = bf2f(a0_[2]); uA3  = bf2f(a0_[3]); \
        uA4 = bf2f(a1_[0]); uA5 = bf2f(a1_[1]); uA6  = bf2f(a1_[2]); uA7  = bf2f(a1_[3]); \
        uA8 = bf2f(a2_[0]); uA9 = bf2f(a2_[1]); uA10 = bf2f(a2_[2]); uA11 = bf2f(a2_[3]); \
        uA12 = bf2f(a3_[0]); uA13 = bf2f(a3_[1]); uA14 = bf2f(a3_[2]); uA15 = bf2f(a3_[3]); \
        uB0 = bf2f(b0_[0]); uB1 = bf2f(b0_[1]); uB2  = bf2f(b0_[2]); uB3  = bf2f(b0_[3]); \
        uB4 = bf2f(b1_[0]); uB5 = bf2f(b1_[1]); uB6  = bf2f(b1_[2]); uB7  = bf2f(b1_[3]); \
        uB8 = bf2f(b2_[0]); uB9 = bf2f(b2_[1]); uB10 = bf2f(b2_[2]); uB11 = bf2f(b2_[3]); \
        uB12 = bf2f(b3_[0]); uB13 = bf2f(b3_[1]); uB14 = bf2f(b3_[2]); uB15 = bf2f(b3_[3]); \
    }

#define DOT16(T, V0, V1, V2, V3, V4, V5, V6, V7, V8, V9, V10, V11, V12, V13, V14, V15, P) \
    {                                                                                   \
        float d0 = T[0] * V0;                                                           \
        d0 = __builtin_fmaf(T[1], V1, d0);                                              \
        d0 = __builtin_fmaf(T[2], V2, d0);                                              \
        d0 = __builtin_fmaf(T[3], V3, d0);                                              \
        float d1 = T[4] * V4;                                                           \
        d1 = __builtin_fmaf(T[5], V5, d1);                                              \
        d1 = __builtin_fmaf(T[6], V6, d1);                                              \
        d1 = __builtin_fmaf(T[7], V7, d1);                                              \
        float d2 = T[8] * V8;                                                           \
        d2 = __builtin_fmaf(T[9], V9, d2);                                              \
        d2 = __builtin_fmaf(T[10], V10, d2);                                            \
        d2 = __builtin_fmaf(T[11], V11, d2);                                            \
        float d3 = T[12] * V12;                                                         \
        d3 = __builtin_fmaf(T[13], V13, d3);                                            \
        d3 = __builtin_fmaf(T[14], V14, d3);                                            \
        d3 = __builtin_fmaf(T[15], V15, d3);                                            \
        P = (d0 + d1) + (d2 + d3);                                                      \
        P += __shfl_xor(P, 32);                                                         \
    }

// one k x BOTH row-halves; OA = rows b32, OB = rows 32+b32 (both full after shfl)
#define KSTEP(A0, A1, OA, OB)                                                           \
    {                                                                                   \
        const int j7 = jj & 7;                                                          \
        const char* jbase = embT + (jj << 12);                                          \
        const short8 vjA0 = *(const short8*)(jbase + (((b32 +       fh0) ^ j7) << 4));  \
        const short8 vjA1 = *(const short8*)(jbase + (((b32 + 128 + fh0) ^ j7) << 4));  \
        const short8 vjB0 = *(const short8*)(jbase + (((b32 + 32  + fh0) ^ j7) << 4));  \
        const short8 vjB1 = *(const short8*)(jbase + (((b32 + 160 + fh0) ^ j7) << 4));  \
        f32x16 tA = __builtin_amdgcn_mfma_f32_32x32x16_bf16(A0, vjA0, zacc, 0, 0, 0);   \
        tA = __builtin_amdgcn_mfma_f32_32x32x16_bf16(A1, vjA1, tA, 0, 0, 0);            \
        f32x16 tB = __builtin_amdgcn_mfma_f32_32x32x16_bf16(A0, vjB0, zacc, 0, 0, 0);   \
        tB = __builtin_amdgcn_mfma_f32_32x32x16_bf16(A1, vjB1, tB, 0, 0, 0);            \
        DOT16(tA, uA0, uA1, uA2, uA3, uA4, uA5, uA6, uA7,                               \
                  uA8, uA9, uA10, uA11, uA12, uA13, uA14, uA15, OA);                    \
        DOT16(tB, uB0, uB1, uB2, uB3, uB4, uB5, uB6, uB7,                               \
                  uB8, uB9, uB10, uB11, uB12, uB13, uB14, uB15, OB);                    \
        ++jj;                                                                           \
        if (jj == NF) { ++ii; jj = ii + 1; RELOAD_VI(); }                               \
    }

// KSTEP + select this lane's half into one named output register
#define KSEL(A0, A1, O)                                                                 \
    {                                                                                   \
        float _pa, _pb;                                                                 \
        KSTEP(A0, A1, _pa, _pb);                                                        \
        O = h32 ? _pb : _pa;                                                            \
    }

// one 2-k group: prefetch next group into N-bank, wait, compute C-bank's 2 k
#define G2(KN, C0, C1, C2, C3, N0, N1, N2, N3, Oa, Ob)                                  \
    LOADW2(N0, N1, N2, N3, KN);                                                         \
    WAITP();                                                                            \
    KSEL(C0, C1, Oa);                                                                   \
    KSEL(C2, C3, Ob);

// 24 k fully unrolled (12 groups, alternating banks); enters with aw = KS group,
// exits with aw = KS+24 group (prefetched by the last line).
#define MEGABLOCK24(KS)                                                                 \
    G2(KS + 2,  aw0, aw1, aw2, aw3, bw0, bw1, bw2, bw3, o0,  o1)                        \
    G2(KS + 4,  bw0, bw1, bw2, bw3, aw0, aw1, aw2, aw3, o2,  o3)                        \
    G2(KS + 6,  aw0, aw1, aw2, aw3, bw0, bw1, bw2, bw3, o4,  o5)                        \
    G2(KS + 8,  bw0, bw1, bw2, bw3, aw0, aw1, aw2, aw3, o6,  o7)                        \
    G2(KS + 10, aw0, aw1, aw2, aw3, bw0, bw1, bw2, bw3, o8,  o9)                        \
    G2(KS + 12, bw0, bw1, bw2, bw3, aw0, aw1, aw2, aw3, o10, o11)                       \
    G2(KS + 14, aw0, aw1, aw2, aw3, bw0, bw1, bw2, bw3, o12, o13)                       \
    G2(KS + 16, bw0, bw1, bw2, bw3, aw0, aw1, aw2, aw3, o14, o15)                       \
    G2(KS + 18, aw0, aw1, aw2, aw3, bw0, bw1, bw2, bw3, o16, o17)                       \
    G2(KS + 20, bw0, bw1, bw2, bw3, aw0, aw1, aw2, aw3, o18, o19)                       \
    G2(KS + 22, aw0, aw1, aw2, aw3, bw0, bw1, bw2, bw3, o20, o21)                       \
    G2(KS + 24, bw0, bw1, bw2, bw3, aw0, aw1, aw2, aw3, o22, o23)

__global__ __launch_bounds__(THREADS, 4) void bil_kernel(const float* __restrict__ emb,
                                                         const unsigned short* __restrict__ wfrag,
                                                         float* __restrict__ out) {
    __shared__ __align__(16) char embT[NF * 4096];   // 163840 B = full LDS pool

    const int tid = threadIdx.x;
    const int btile = blockIdx.x & 127;   // pair-mates bid, bid+128 -> same XCD (bid%8)
    const int khalf = blockIdx.x >> 7;    // 0: k 0..383, 1: k 384..779
    const int b0 = btile * BT;

    // --- Stage 64-row tile: coalesced 32B global reads, swizzled LDS writes ---
    for (int u = tid; u < BT * 160; u += THREADS) {
        const int bb = u / 160;
        const int t = u - 160 * bb;
        const int field = t >> 2;
        const int fq = t & 3;
        const float* src = emb + (size_t)(b0 + bb) * (NF * 32) + field * 32 + 8 * fq;
        const float4 x0 = *(const float4*)src;
        const float4 x1 = *(const float4*)(src + 4);
        short8 v;
        v[0] = (short)f2bf(x0.x); v[1] = (short)f2bf(x0.y);
        v[2] = (short)f2bf(x0.z); v[3] = (short)f2bf(x0.w);
        v[4] = (short)f2bf(x1.x); v[5] = (short)f2bf(x1.y);
        v[6] = (short)f2bf(x1.z); v[7] = (short)f2bf(x1.w);
        const int g = (bb + 64 * fq) ^ (field & 7);
        *(short8*)(embT + field * 4096 + g * 16) = v;
    }
    __syncthreads();

    const int ww = tid >> 6;            // wave 0..15
    const int l = tid & 63;
    const int b32 = l & 31;
    const int h32 = l >> 5;
    const int fh0 = 64 * h32;
    const int eoff = 8 * h32;

    const f32x16 zacc = {};

    // khalf0: waves get k [24*ww, 24*ww+24)  (16x24 = 384)
    // khalf1: base 384; waves 0..14 get 24 k, wave 15 gets 36 k (744..779)
    const int ks = khalf * 384 + ww * 24;

    int ii = 0, jj;                     // (i,j) for k = ks, i-major triu order
    {
        int kk = ks, len = 39;
        while (kk >= len) { kk -= len; ++ii; --len; }
        jj = ii + 1 + kk;
    }

    float uA0, uA1, uA2, uA3, uA4, uA5, uA6, uA7;
    float uA8, uA9, uA10, uA11, uA12, uA13, uA14, uA15;
    float uB0, uB1, uB2, uB3, uB4, uB5, uB6, uB7;
    float uB8, uB9, uB10, uB11, uB12, uB13, uB14, uB15;
    RELOAD_VI();

    const char* wbase = (const char*)wfrag + l * 16;
    const size_t orowoff = (size_t)(b0 + 32 * h32 + b32) * NK;  // lane's output row
    float* orow = out + orowoff + ks;

    short8 aw0, aw1, aw2, aw3;          // bank A
    short8 bw0, bw1, bw2, bw3;          // bank B
    LOADW2(aw0, aw1, aw2, aw3, ks);

    {
        float o0, o1, o2, o3, o4, o5, o6, o7, o8, o9, o10, o11;
        float o12, o13, o14, o15, o16, o17, o18, o19, o20, o21, o22, o23;
        MEGABLOCK24(ks)
        float4 s;                       // 96 contiguous, 16B-aligned bytes per lane
        s.x = o0;  s.y = o1;  s.z = o2;  s.w = o3;  *(float4*)(orow)      = s;
        s.x = o4;  s.y = o5;  s.z = o6;  s.w = o7;  *(float4*)(orow + 4)  = s;
        s.x = o8;  s.y = o9;  s.z = o10; s.w = o11; *(float4*)(orow + 8)  = s;
        s.x = o12; s.y = o13; s.z = o14; s.w = o15; *(float4*)(orow + 12) = s;
        s.x = o16; s.y = o17; s.z = o18; s.w = o19; *(float4*)(orow + 16) = s;
        s.x = o20; s.y = o21; s.z = o22; s.w = o23; *(float4*)(orow + 20) = s;
    }

    if (khalf == 1 && ww == 15) {       // 12-k tail 768..779; aw already holds 768's group
        float o0, o1, o2, o3, o4, o5, o6, o7, o8, o9, o10, o11;
        G2(770, aw0, aw1, aw2, aw3, bw0, bw1, bw2, bw3, o0, o1)
        G2(772, bw0, bw1, bw2, bw3, aw0, aw1, aw2, aw3, o2, o3)
        G2(774, aw0, aw1, aw2, aw3, bw0, bw1, bw2, bw3, o4, o5)
        G2(776, bw0, bw1, bw2, bw3, aw0, aw1, aw2, aw3, o6, o7)
        G2(778, aw0, aw1, aw2, aw3, bw0, bw1, bw2, bw3, o8, o9)
        WAIT0();
        KSEL(bw0, bw1, o10);
        KSEL(bw2, bw3, o11);
        float* trow = out + orowoff + 768;
        float4 s;
        s.x = o0; s.y = o1; s.z = o2;  s.w = o3;  *(float4*)(trow)     = s;
        s.x = o4; s.y = o5; s.z = o6;  s.w = o7;  *(float4*)(trow + 4) = s;
        s.x = o8; s.y = o9; s.z = o10; s.w = o11; *(float4*)(trow + 8) = s;
    }
}

extern "C" void kernel_launch(void* const* d_in, const int* in_sizes, int n_in,
                              void* d_out, int out_size, void* d_ws, size_t ws_size,
                              hipStream_t stream) {
    const float* emb = (const float*)d_in[0];
    const float* W   = (const float*)d_in[1];
    float* out = (float*)d_out;
    unsigned short* wfrag = (unsigned short*)d_ws;   // 780*2048 B = 1.6 MB scratch

    wprep_kernel<<<dim3(NK), dim3(128), 0, stream>>>(W, wfrag);
    bil_kernel<<<dim3(256), dim3(THREADS), 0, stream>>>(emb, wfrag, out);
}

// Round 12
// 41.772 us; speedup vs baseline: 1.4304x; 1.4304x over previous
//
#include <hip/hip_runtime.h>
#include <cstdint>
#include <cstddef>

typedef __attribute__((ext_vector_type(8))) short short8;
typedef __attribute__((ext_vector_type(4))) unsigned short ushort4_t;
typedef __attribute__((ext_vector_type(16))) float f32x16;

#define NF 40
#define NK 780           // 40*39/2 pairs
#define BT 32            // batch rows per block
#define THREADS 1024     // 16 waves, grid 256 = 1 block/CU

__device__ __forceinline__ unsigned short f2bf(float f) {
    unsigned int u = __float_as_uint(f);
    u = (u + 0x7fffu + ((u >> 16) & 1u)) >> 16;
    return (unsigned short)u;
}
__device__ __forceinline__ float bf2f(unsigned short x) {
    return __uint_as_float(((unsigned int)x) << 16);
}

// wfrag[k][half][l][t] = bf16( W[k][ e = l&31 ][ 16*half + 8*(l>>5) + t ] )
__global__ __launch_bounds__(128) void wprep_kernel(const float* __restrict__ W,
                                                    unsigned short* __restrict__ wfrag) {
    const int k = blockIdx.x, t = threadIdx.x;
    const int half = t >> 6, l = t & 63;
    const int e = l & 31;
    const int f0 = 16 * half + 8 * (l >> 5);
    const float* src = W + (size_t)k * 1024 + e * 32 + f0;
    const float4 x0 = *(const float4*)src;
    const float4 x1 = *(const float4*)(src + 4);
    short8 v;
    v[0] = (short)f2bf(x0.x); v[1] = (short)f2bf(x0.y);
    v[2] = (short)f2bf(x0.z); v[3] = (short)f2bf(x0.w);
    v[4] = (short)f2bf(x1.x); v[5] = (short)f2bf(x1.y);
    v[6] = (short)f2bf(x1.z); v[7] = (short)f2bf(x1.w);
    *(short8*)(wfrag + (size_t)k * 1024 + half * 512 + l * 8) = v;
}

// --- forced-pipeline primitives -------------------------------------------------
__device__ __forceinline__ void ld_w4(short8& r0, short8& r1, short8& r2, short8& r3,
                                      const char* addr) {
    asm volatile("global_load_dwordx4 %0, %4, off\n\t"
                 "global_load_dwordx4 %1, %4, off offset:1024\n\t"
                 "global_load_dwordx4 %2, %4, off offset:2048\n\t"
                 "global_load_dwordx4 %3, %4, off offset:3072"
                 : "=&v"(r0), "=&v"(r1), "=&v"(r2), "=&v"(r3)
                 : "v"(addr));
}
#define WAITP() do { asm volatile("s_waitcnt vmcnt(4)" ::: "memory"); \
                     __builtin_amdgcn_sched_barrier(0); } while (0)
#define WAIT0() do { asm volatile("s_waitcnt vmcnt(0)" ::: "memory"); \
                     __builtin_amdgcn_sched_barrier(0); } while (0)

#define LOADW2(R0, R1, R2, R3, KB)                                                      \
    {                                                                                   \
        const int kbc = (KB) > 778 ? 778 : (KB);                                        \
        ld_w4(R0, R1, R2, R3, wbase + ((size_t)kbc << 11));                             \
    }

// embT granule (field, g): g = (b + 32*fq) ^ (field&7); bf16 of
// emb[b0+b][field][8*fq..8*fq+7]. 2048 B per field.

#define RELOAD_VI()                                                                     \
    {                                                                                   \
        const int i7 = ii & 7;                                                          \
        const char* ibase = embT + (ii << 11) + eoff;                                   \
        const ushort4_t r0 = *(const ushort4_t*)(ibase + (((b32     ) ^ i7) << 4));     \
        const ushort4_t r1 = *(const ushort4_t*)(ibase + (((b32 + 32) ^ i7) << 4));     \
        const ushort4_t r2 = *(const ushort4_t*)(ibase + (((b32 + 64) ^ i7) << 4));     \
        const ushort4_t r3 = *(const ushort4_t*)(ibase + (((b32 + 96) ^ i7) << 4));     \
        vf0  = bf2f(r0[0]); vf1  = bf2f(r0[1]); vf2  = bf2f(r0[2]); vf3  = bf2f(r0[3]); \
        vf4  = bf2f(r1[0]); vf5  = bf2f(r1[1]); vf6  = bf2f(r1[2]); vf7  = bf2f(r1[3]); \
        vf8  = bf2f(r2[0]); vf9  = bf2f(r2[1]); vf10 = bf2f(r2[2]); vf11 = bf2f(r2[3]); \
        vf12 = bf2f(r3[0]); vf13 = bf2f(r3[1]); vf14 = bf2f(r3[2]); vf15 = bf2f(r3[3]); \
    }

// one k: t[e,b] = W[k]·vj (2 chained 32x32x16 over f-halves), tree-dot with cached vi
#define KSTEP(A0, A1, OREG)                                                             \
    {                                                                                   \
        const int j7 = jj & 7;                                                          \
        const char* jbase = embT + (jj << 11);                                          \
        const short8 vj0 = *(const short8*)(jbase + (((b32 + fq0) ^ j7) << 4));         \
        const short8 vj1 = *(const short8*)(jbase + (((b32 + fq1) ^ j7) << 4));         \
        f32x16 t = __builtin_amdgcn_mfma_f32_32x32x16_bf16(A0, vj0, zacc, 0, 0, 0);     \
        t = __builtin_amdgcn_mfma_f32_32x32x16_bf16(A1, vj1, t, 0, 0, 0);               \
        float c0 = t[0] * vf0;                                                          \
        c0 = __builtin_fmaf(t[1], vf1, c0);                                             \
        c0 = __builtin_fmaf(t[2], vf2, c0);                                             \
        c0 = __builtin_fmaf(t[3], vf3, c0);                                             \
        float c1 = t[4] * vf4;                                                          \
        c1 = __builtin_fmaf(t[5], vf5, c1);                                             \
        c1 = __builtin_fmaf(t[6], vf6, c1);                                             \
        c1 = __builtin_fmaf(t[7], vf7, c1);                                             \
        float c2 = t[8] * vf8;                                                          \
        c2 = __builtin_fmaf(t[9], vf9, c2);                                             \
        c2 = __builtin_fmaf(t[10], vf10, c2);                                           \
        c2 = __builtin_fmaf(t[11], vf11, c2);                                           \
        float c3 = t[12] * vf12;                                                        \
        c3 = __builtin_fmaf(t[13], vf13, c3);                                           \
        c3 = __builtin_fmaf(t[14], vf14, c3);                                           \
        c3 = __builtin_fmaf(t[15], vf15, c3);                                           \
        float p = (c0 + c1) + (c2 + c3);                                                \
        p += __shfl_xor(p, 32);                                                         \
        OREG = p;                                                                       \
        ++jj;                                                                           \
        if (jj == NF) { ++ii; jj = ii + 1; RELOAD_VI(); }                               \
    }

// set (ii, jj) for arbitrary k via closed form + integer guards, then reload vi cache
#define SETIJ(K)                                                                        \
    {                                                                                   \
        const int k_ = (K);                                                             \
        int i_ = (int)((79.0f - __builtin_sqrtf((float)(6241 - 8 * k_))) * 0.5f);       \
        if (i_ < 0) i_ = 0;                                                             \
        while ((i_ + 1) * (78 - i_) / 2 <= k_) ++i_;                                    \
        while (i_ * (79 - i_) / 2 > k_) --i_;                                           \
        ii = i_;                                                                        \
        jj = i_ + 1 + (k_ - i_ * (79 - i_) / 2);                                        \
        RELOAD_VI();                                                                    \
    }

// 8-k chunk: 4 pipelined 2-k groups; enters with bank A = this chunk's first group,
// exits with bank A = KNEXT's group. Stores 32 contiguous bytes per row.
#define CHUNK8(K0, KNEXT)                                                               \
    {                                                                                   \
        float o0, o1, o2, o3, o4, o5, o6, o7;                                           \
        LOADW2(bw0, bw1, bw2, bw3, (K0) + 2); WAITP();                                  \
        KSTEP(aw0, aw1, o0); KSTEP(aw2, aw3, o1);                                       \
        LOADW2(aw0, aw1, aw2, aw3, (K0) + 4); WAITP();                                  \
        KSTEP(bw0, bw1, o2); KSTEP(bw2, bw3, o3);                                       \
        LOADW2(bw0, bw1, bw2, bw3, (K0) + 6); WAITP();                                  \
        KSTEP(aw0, aw1, o4); KSTEP(aw2, aw3, o5);                                       \
        LOADW2(aw0, aw1, aw2, aw3, (KNEXT)); WAITP();                                   \
        KSTEP(bw0, bw1, o6); KSTEP(bw2, bw3, o7);                                       \
        if (l < 32) {                                                                   \
            float* orow = out + orowbase + (K0);                                        \
            float4 s;                                                                   \
            s.x = o0; s.y = o1; s.z = o2; s.w = o3; *(float4*)orow = s;                 \
            s.x = o4; s.y = o5; s.z = o6; s.w = o7; *(float4*)(orow + 4) = s;           \
        }                                                                               \
    }

__global__ __launch_bounds__(THREADS, 4) void bil_kernel(const float* __restrict__ emb,
                                                         const unsigned short* __restrict__ wfrag,
                                                         float* __restrict__ out) {
    __shared__ __align__(16) char embT[NF * 2048];   // 81920 B

    const int tid = threadIdx.x;
    const int b0 = blockIdx.x * BT;

    // --- Stage 32-row tile: coalesced 32B global reads, swizzled LDS writes ---
    for (int u = tid; u < BT * 160; u += THREADS) {  // exactly 5 iterations
        const int bb = u / 160;
        const int t = u - 160 * bb;
        const int field = t >> 2;
        const int fq = t & 3;
        const float* src = emb + (size_t)(b0 + bb) * (NF * 32) + field * 32 + 8 * fq;
        const float4 x0 = *(const float4*)src;
        const float4 x1 = *(const float4*)(src + 4);
        short8 v;
        v[0] = (short)f2bf(x0.x); v[1] = (short)f2bf(x0.y);
        v[2] = (short)f2bf(x0.z); v[3] = (short)f2bf(x0.w);
        v[4] = (short)f2bf(x1.x); v[5] = (short)f2bf(x1.y);
        v[6] = (short)f2bf(x1.z); v[7] = (short)f2bf(x1.w);
        const int g = (bb + 32 * fq) ^ (field & 7);
        *(short8*)(embT + field * 2048 + g * 16) = v;
    }
    __syncthreads();

    const int ww = tid >> 6;            // wave 0..15
    const int l = tid & 63;
    const int b32 = l & 31;             // lane's batch row (C col)
    const int h32 = l >> 5;
    const int fq0 = 32 * h32;           // vj granule offset, f-half 0
    const int fq1 = 64 + 32 * h32;      // f-half 1
    const int eoff = 8 * h32;           // byte offset within vi granule

    const f32x16 zacc = {};

    int ii, jj;
    float vf0, vf1, vf2, vf3, vf4, vf5, vf6, vf7;
    float vf8, vf9, vf10, vf11, vf12, vf13, vf14, vf15;

    const char* wbase = (const char*)wfrag + l * 16;
    const size_t orowbase = (size_t)(b0 + b32) * NK;

    short8 aw0, aw1, aw2, aw3;          // bank A
    short8 bw0, bw1, bw2, bw3;          // bank B

    // Interleaved chunk schedule: wave ww does chunks c = ww + 16m (m = 0..5),
    // i.e. k0 = 8c; all 16 waves (and all CUs) share a sliding ~256 KB W-window.
    LOADW2(aw0, aw1, aw2, aw3, 8 * ww);
    int c = ww;
#pragma unroll 1
    for (int m = 0; m < 6; ++m) {
        const int k0 = 8 * c;
        SETIJ(k0);
        const int knext = (m < 5) ? (k0 + 128) : ((ww < 3) ? (768 + 4 * ww) : 768);
        CHUNK8(k0, knext);
        c += 16;
    }
    // Remainder k 768..779: 4-k blocks for waves 0..2 (bank A already holds k0r group).
    if (ww < 3) {
        const int k0r = 768 + 4 * ww;
        SETIJ(k0r);
        float o0, o1, o2, o3;
        LOADW2(bw0, bw1, bw2, bw3, k0r + 2);
        WAITP();
        KSTEP(aw0, aw1, o0); KSTEP(aw2, aw3, o1);
        WAIT0();
        KSTEP(bw0, bw1, o2); KSTEP(bw2, bw3, o3);
        if (l < 32) {
            float4 s; s.x = o0; s.y = o1; s.z = o2; s.w = o3;
            *(float4*)(out + orowbase + k0r) = s;
        }
    }
}

extern "C" void kernel_launch(void* const* d_in, const int* in_sizes, int n_in,
                              void* d_out, int out_size, void* d_ws, size_t ws_size,
                              hipStream_t stream) {
    const float* emb = (const float*)d_in[0];
    const float* W   = (const float*)d_in[1];
    float* out = (float*)d_out;
    unsigned short* wfrag = (unsigned short*)d_ws;   // 780*2048 B = 1.6 MB scratch

    wprep_kernel<<<dim3(NK), dim3(128), 0, stream>>>(W, wfrag);
    bil_kernel<<<dim3(8192 / BT), dim3(THREADS), 0, stream>>>(emb, wfrag, out);
}